// Round 9
// baseline (5103.285 us; speedup 1.0000x reference)
//
#include <hip/hip_runtime.h>

// Problem constants (B=64, T=512, D=256, Q=8, K=1024)
#define NTOK   32768
#define DDIM   256
#define KCODES 1024
#define QLAYERS 8

#define MT     64               // tokens per block
#define NCODE  32               // codes per K-iteration
#define NCH    (KCODES / NCODE)
#define DELTA  4e-4f            // cert margin >> f16-screen worst-case error
#define NBLK   (NTOK / MT)      // 512 blocks

typedef __attribute__((ext_vector_type(8))) _Float16 f16x8;
typedef __attribute__((ext_vector_type(4))) float f32x4;

// d_out: [0,N*D) residual->output | [N*D] loss | [N*D+1,+Q*N) indices (as float)
// d_ws : eh16 [Q*K*D f16, x256-scaled, LINEAR] | ce [Q*K f32] | loss_part [Q*NBLK f32]

__global__ void ce_kernel(const float* __restrict__ emb, float* __restrict__ ce) {
  int gid  = blockIdx.x * blockDim.x + threadIdx.x;
  int code = gid >> 6;
  int lane = threadIdx.x & 63;
  float4 v = reinterpret_cast<const float4*>(emb + (size_t)code * DDIM)[lane];
  float s = v.x * v.x + v.y * v.y + v.z * v.z + v.w * v.w;
#pragma unroll
  for (int off = 32; off; off >>= 1) s += __shfl_xor(s, off);
  if (lane == 0) ce[code] = s;
}

// f16 conversion of codebooks, scaled by 256 (avoids f16 denormals), LINEAR layout
__global__ void split16_kernel(const float* __restrict__ emb, _Float16* __restrict__ eh) {
  int g  = blockIdx.x * blockDim.x + threadIdx.x;   // Q*K*32
  int c  = g >> 5;
  int dg = g & 31;
  const float4* p = reinterpret_cast<const float4*>(emb + (size_t)c * DDIM + dg * 8);
  float4 a = p[0], b = p[1];
  f16x8 h;
  h[0] = (_Float16)(a.x * 256.f); h[1] = (_Float16)(a.y * 256.f);
  h[2] = (_Float16)(a.z * 256.f); h[3] = (_Float16)(a.w * 256.f);
  h[4] = (_Float16)(b.x * 256.f); h[5] = (_Float16)(b.y * 256.f);
  h[6] = (_Float16)(b.z * 256.f); h[7] = (_Float16)(b.w * 256.f);
  *reinterpret_cast<f16x8*>(eh + (size_t)c * DDIM + (size_t)dg * 8) = h;
}

__global__ void init_kernel(const float* __restrict__ x, float* __restrict__ res) {
  size_t i = (size_t)blockIdx.x * blockDim.x + threadIdx.x;
  reinterpret_cast<float4*>(res)[i] = reinterpret_cast<const float4*>(x)[i];
}

// top-2 insert, value-only (codes visited ascending per lane -> strict < keeps first)
__device__ __forceinline__ void ins2(float d, int c, float v[2], int ci[2]) {
  bool l1 = d < v[1];
  bool l0 = d < v[0];
  v[1] = l0 ? v[0] : (l1 ? d : v[1]);  ci[1] = l0 ? ci[0] : (l1 ? c : ci[1]);
  v[0] = l0 ? d : v[0];                ci[0] = l0 ? c : ci[0];
}

// top-2 insert with lexicographic tie-break (value, then lower index)
__device__ __forceinline__ void lexins2(float d, int c, float v[2], int ci[2]) {
  bool l1 = (d < v[1]) || (d == v[1] && c < ci[1]);
  bool l0 = (d < v[0]) || (d == v[0] && c < ci[0]);
  v[1] = l0 ? v[0] : (l1 ? d : v[1]);  ci[1] = l0 ? ci[0] : (l1 ? c : ci[1]);
  v[0] = l0 ? d : v[0];                ci[0] = l0 ? c : ci[0];
}

__global__ __attribute__((amdgpu_flat_work_group_size(256, 256), amdgpu_waves_per_eu(2, 2)))
void vq_layer_kernel(const float* __restrict__ emb,      // this layer's fp32 codebook
                     const _Float16* __restrict__ eh16,  // this layer's f16 codebook
                     const float* __restrict__ ce,       // this layer's ||e||^2
                     float* __restrict__ res,            // residual (in d_out)
                     float* __restrict__ idx_out,        // this layer's index slice
                     float* __restrict__ loss_part) {    // this layer's partials [NBLK]
  __shared__ __align__(16) float ce_s[KCODES];   // 4 KB
  __shared__ float cf_s[MT];
  __shared__ float t2v[2][MT][2];
  __shared__ int   t2i[2][MT][2];
  __shared__ int   idx_s[MT];
  __shared__ float rr_v[256];
  __shared__ int   rr_i[256];
  __shared__ unsigned long long fullmask;
  __shared__ float wsum[4];

  const int t    = threadIdx.x;
  const int lane = t & 63, w = t >> 6;
  const int tg   = w & 1;          // token-group: tokens [tg*32, tg*32+32)
  const int ch   = w >> 1;         // code-half of each 32-code K-iter
  const int l15  = lane & 15, lq = lane >> 4;
  const int tok0 = blockIdx.x * MT;

  // stage ce for the layer
  reinterpret_cast<float4*>(ce_s)[t] = reinterpret_cast<const float4*>(ce)[t];

  // ---- cf = ||res||^2 (EXACT r1 arithmetic, res from global) ----
  {
    const int m = t >> 2, p = t & 3;
    const float4* r4 =
        reinterpret_cast<const float4*>(res + (size_t)(tok0 + m) * DDIM + p * 64);
    float s = 0.f;
#pragma unroll
    for (int j = 0; j < 16; ++j) {
      float4 v = r4[j];
      s = fmaf(v.x, v.x, s); s = fmaf(v.y, v.y, s);
      s = fmaf(v.z, v.z, s); s = fmaf(v.w, v.w, s);
    }
    s += __shfl_xor(s, 1);
    s += __shfl_xor(s, 2);
    if (p == 0) cf_s[m] = s;
  }

  // ---- A-split: wave covers tokens [tg*32, tg*32+32) as 2 MFMA frags ----
  f16x8 af[2][8];
#pragma unroll
  for (int mi = 0; mi < 2; ++mi)
#pragma unroll
    for (int ds = 0; ds < 8; ++ds) {
      const float* pr =
          res + (size_t)(tok0 + tg * 32 + mi * 16 + l15) * DDIM + ds * 32 + lq * 8;
      float4 a = *reinterpret_cast<const float4*>(pr);
      float4 b = *reinterpret_cast<const float4*>(pr + 4);
      f16x8 h;
      h[0] = (_Float16)a.x; h[1] = (_Float16)a.y; h[2] = (_Float16)a.z; h[3] = (_Float16)a.w;
      h[4] = (_Float16)b.x; h[5] = (_Float16)b.y; h[6] = (_Float16)b.z; h[7] = (_Float16)b.w;
      af[mi][ds] = h;
    }

  __syncthreads();   // B1: cf_s/ce_s visible

  float cfreg[2][4];
#pragma unroll
  for (int mi = 0; mi < 2; ++mi)
#pragma unroll
    for (int r = 0; r < 4; ++r) cfreg[mi][r] = cf_s[tg * 32 + mi * 16 + lq * 4 + r];

  float tv[8][2]; int ti[8][2];
#pragma unroll
  for (int s = 0; s < 8; ++s) {
    tv[s][0] = 3.4e38f; tv[s][1] = 3.4e38f; ti[s][0] = 0; ti[s][1] = 0;
  }

  // ---- K-loop: ZERO barriers, ZERO LDS. B direct global->VGPR, reg dbuf.
  //      Per-layer dispatch keeps all blocks on the same 512 KB slice -> L2-resident.
  const _Float16* bp = eh16 + (size_t)(ch * 16 + l15) * DDIM + lq * 8;
  uint4 bcur[8];
#pragma unroll
  for (int i = 0; i < 8; ++i)
    bcur[i] = *reinterpret_cast<const uint4*>(bp + i * 32);

  for (int kc = 0; kc < NCH; ++kc) {
    uint4 bnxt[8];
    if (kc + 1 < NCH) {
      const _Float16* bnp = bp + (size_t)(kc + 1) * NCODE * DDIM;
#pragma unroll
      for (int i = 0; i < 8; ++i)
        bnxt[i] = *reinterpret_cast<const uint4*>(bnp + i * 32);
    }

    f32x4 acc[2][2];
#pragma unroll
    for (int mi = 0; mi < 2; ++mi)
#pragma unroll
      for (int p = 0; p < 2; ++p) acc[mi][p] = (f32x4){0.f, 0.f, 0.f, 0.f};

#pragma unroll
    for (int ds = 0; ds < 8; ++ds) {
      f16x8 b = __builtin_bit_cast(f16x8, bcur[ds]);
      acc[0][ds & 1] = __builtin_amdgcn_mfma_f32_16x16x32_f16(af[0][ds], b, acc[0][ds & 1], 0, 0, 0);
      acc[1][ds & 1] = __builtin_amdgcn_mfma_f32_16x16x32_f16(af[1][ds], b, acc[1][ds & 1], 0, 0, 0);
    }

    const int   cg  = kc * NCODE + ch * 16 + l15;
    const float cev = ce_s[cg];
#pragma unroll
    for (int mi = 0; mi < 2; ++mi)
#pragma unroll
      for (int r = 0; r < 4; ++r) {
        float dot = acc[mi][0][r] + acc[mi][1][r];   // dot * 256
        float d   = fmaf(-0.0078125f, dot, cfreg[mi][r] + cev);
        ins2(d, cg, tv[mi * 4 + r], ti[mi * 4 + r]);
      }

    if (kc + 1 < NCH) {
#pragma unroll
      for (int i = 0; i < 8; ++i) bcur[i] = bnxt[i];
    }
  }

  // ---- merge top-2 across the 16-lane code group ----
#pragma unroll
  for (int s = 0; s < 8; ++s) {
#pragma unroll
    for (int off = 1; off <= 8; off <<= 1) {
      float a0 = __shfl_xor(tv[s][0], off), a1 = __shfl_xor(tv[s][1], off);
      int   b0 = __shfl_xor(ti[s][0], off), b1 = __shfl_xor(ti[s][1], off);
      lexins2(a0, b0, tv[s], ti[s]);
      lexins2(a1, b1, tv[s], ti[s]);
    }
    if (l15 == 0) {
      const int mi = s >> 2, r = s & 3;
      const int tok = tg * 32 + mi * 16 + lq * 4 + r;
      t2v[ch][tok][0] = tv[s][0]; t2v[ch][tok][1] = tv[s][1];
      t2i[ch][tok][0] = ti[s][0]; t2i[ch][tok][1] = ti[s][1];
    }
  }
  __syncthreads();   // B2: t2 visible

  // ---- classify: certified unique or full exact re-rank (deterministic ballot) ----
  if (t < MT) {
    float v[2]; int ci[2];
    v[0]  = t2v[0][t][0]; v[1]  = t2v[0][t][1];
    ci[0] = t2i[0][t][0]; ci[1] = t2i[0][t][1];
    lexins2(t2v[1][t][0], t2i[1][t][0], v, ci);
    lexins2(t2v[1][t][1], t2i[1][t][1], v, ci);
    idx_s[t] = ci[0];
    unsigned long long bm = __ballot(v[1] - v[0] < DELTA);
    if (t == 0) fullmask = bm;
  }
  __syncthreads();   // B3: idx_s/fullmask visible

  // ---- full exact re-rank for near-tie tokens (proven np-matching path) ----
  unsigned long long fm = fullmask;
  while (fm) {
    const int f = __builtin_ctzll(fm);
    fm &= fm - 1;
    const float cfv = cf_s[f];
    const float* rrow = res + (size_t)(tok0 + f) * DDIM;
    float bestv = 3.4e38f; int besti = 0;
#pragma unroll
    for (int u = 0; u < 4; ++u) {
      int c = t * 4 + u;
      const float4* e4 = reinterpret_cast<const float4*>(emb + (size_t)c * DDIM);
      float acc = 0.f;
#pragma unroll 8
      for (int j = 0; j < 64; ++j) {
        float4 b = e4[j];
        float4 a = *reinterpret_cast<const float4*>(rrow + j * 4);
        acc = fmaf(a.x, b.x, acc); acc = fmaf(a.y, b.y, acc);
        acc = fmaf(a.z, b.z, acc); acc = fmaf(a.w, b.w, acc);
      }
      float dist = (cfv + ce_s[c]) - 2.0f * acc;
      if (dist < bestv) { bestv = dist; besti = c; }
    }
    rr_v[t] = bestv; rr_i[t] = besti;
    __syncthreads();
    if (t < 64) {
      float vb = rr_v[t]; int ib = rr_i[t];
#pragma unroll
      for (int s = 64; s < 256; s += 64) {
        float ov = rr_v[t + s]; int oi = rr_i[t + s];
        if (ov < vb || (ov == vb && oi < ib)) { vb = ov; ib = oi; }
      }
#pragma unroll
      for (int off = 1; off < 64; off <<= 1) {
        float ov = __shfl_xor(vb, off); int oi = __shfl_xor(ib, off);
        if (ov < vb || (ov == vb && oi < ib)) { vb = ov; ib = oi; }
      }
      if (t == 0) idx_s[f] = ib;
    }
    __syncthreads();
  }

  if (t < MT) idx_out[tok0 + t] = (float)idx_s[t];

  // ---- residual update (global) + loss partial ----
  {
    const int m = t >> 2, p = t & 3;
    const int ci = idx_s[m];
    const float4* e4 = reinterpret_cast<const float4*>(emb + (size_t)ci * DDIM + p * 64);
    float4* r4 = reinterpret_cast<float4*>(res + (size_t)(tok0 + m) * DDIM + p * 64);
    float s = 0.f;
#pragma unroll
    for (int j = 0; j < 16; ++j) {
      float4 r = r4[j], e = e4[j];
      float4 nr = make_float4(r.x - e.x, r.y - e.y, r.z - e.z, r.w - e.w);
      s = fmaf(nr.x, nr.x, s); s = fmaf(nr.y, nr.y, s);
      s = fmaf(nr.z, nr.z, s); s = fmaf(nr.w, nr.w, s);
      r4[j] = nr;
    }
#pragma unroll
    for (int off = 32; off; off >>= 1) s += __shfl_xor(s, off);
    if ((t & 63) == 0) wsum[w] = s;
  }
  __syncthreads();
  if (t == 0) loss_part[blockIdx.x] = wsum[0] + wsum[1] + wsum[2] + wsum[3];
}

__global__ void final_kernel(const float* __restrict__ x, float* __restrict__ out) {
  size_t i = (size_t)blockIdx.x * blockDim.x + threadIdx.x;
  float4 xv = reinterpret_cast<const float4*>(x)[i];
  float4 r  = reinterpret_cast<float4*>(out)[i];
  reinterpret_cast<float4*>(out)[i] =
      make_float4(xv.x - r.x, xv.y - r.y, xv.z - r.z, xv.w - r.w);
}

__global__ void loss_final_kernel(const float* __restrict__ part, float* __restrict__ loss_out) {
  int t = threadIdx.x;   // 64 threads, QLAYERS*NBLK = 4096 partials
  float s = 0.f;
#pragma unroll
  for (int j = 0; j < QLAYERS * NBLK / 64; ++j) s += part[j * 64 + t];
#pragma unroll
  for (int off = 32; off; off >>= 1) s += __shfl_xor(s, off);
  if (t == 0) *loss_out = s * (1.25f / ((float)NTOK * (float)DDIM));
}

extern "C" void kernel_launch(void* const* d_in, const int* in_sizes, int n_in,
                              void* d_out, int out_size, void* d_ws, size_t ws_size,
                              hipStream_t stream) {
  const float* x   = (const float*)d_in[0];
  const float* emb = (const float*)d_in[1];
  float* out      = (float*)d_out;          // doubles as residual buffer
  float* loss     = out + (size_t)NTOK * DDIM;
  float* idx_base = loss + 1;

  _Float16* eh16   = (_Float16*)d_ws;                                   // 4 MB
  float* ce        = (float*)(eh16 + (size_t)QLAYERS * KCODES * DDIM);  // 32 KB
  float* loss_part = ce + (size_t)QLAYERS * KCODES;                     // 16 KB

  split16_kernel<<<QLAYERS * KCODES * 32 / 256, 256, 0, stream>>>(emb, eh16);
  ce_kernel<<<QLAYERS * KCODES * 64 / 256, 256, 0, stream>>>(emb, ce);
  init_kernel<<<NTOK * DDIM / 4 / 256, 256, 0, stream>>>(x, out);
  for (int q = 0; q < QLAYERS; ++q) {
    vq_layer_kernel<<<NBLK, 256, 0, stream>>>(
        emb + (size_t)q * KCODES * DDIM, eh16 + (size_t)q * KCODES * DDIM,
        ce + (size_t)q * KCODES, out,
        idx_base + (size_t)q * NTOK, loss_part + (size_t)q * NBLK);
  }
  final_kernel<<<NTOK * DDIM / 4 / 256, 256, 0, stream>>>(x, out);
  loss_final_kernel<<<1, 64, 0, stream>>>(loss_part, loss);
}

// Round 10
// 2422.634 us; speedup vs baseline: 2.1065x; 2.1065x over previous
//
#include <hip/hip_runtime.h>

// Problem constants (B=64, T=512, D=256, Q=8, K=1024)
#define NTOK   32768
#define DDIM   256
#define KCODES 1024
#define QLAYERS 8

#define MT     64               // tokens per block
#define NCHUNK 64               // codes staged per chunk
#define NCH    (KCODES / NCHUNK)
#define DELTA  1e-4f            // cert margin ~10 sigma of f16-screen error
#define NBLK   (NTOK / MT)      // 512 blocks

typedef __attribute__((ext_vector_type(8))) _Float16 f16x8;
typedef __attribute__((ext_vector_type(4))) float f32x4;

// d_out: [0,N*D) residual->output | [N*D] loss | [N*D+1,+Q*N) indices (as float)
// d_ws : eh16 [Q*K*D f16, x256-scaled, swizzled] | ce [Q*K f32] | loss_part [Q*NBLK f32]

__global__ void ce_kernel(const float* __restrict__ emb, float* __restrict__ ce) {
  int gid  = blockIdx.x * blockDim.x + threadIdx.x;
  int code = gid >> 6;
  int lane = threadIdx.x & 63;
  float4 v = reinterpret_cast<const float4*>(emb + (size_t)code * DDIM)[lane];
  float s = v.x * v.x + v.y * v.y + v.z * v.z + v.w * v.w;
#pragma unroll
  for (int off = 32; off; off >>= 1) s += __shfl_xor(s, off);
  if (lane == 0) ce[code] = s;
}

// f16 conversion of codebooks, scaled by 256, 16B-group XOR swizzle baked in
__global__ void split16_kernel(const float* __restrict__ emb, _Float16* __restrict__ eh) {
  int g  = blockIdx.x * blockDim.x + threadIdx.x;   // Q*K*32
  int c  = g >> 5;
  int dg = g & 31;
  const float4* p = reinterpret_cast<const float4*>(emb + (size_t)c * DDIM + dg * 8);
  float4 a = p[0], b = p[1];
  f16x8 h;
  h[0] = (_Float16)(a.x * 256.f); h[1] = (_Float16)(a.y * 256.f);
  h[2] = (_Float16)(a.z * 256.f); h[3] = (_Float16)(a.w * 256.f);
  h[4] = (_Float16)(b.x * 256.f); h[5] = (_Float16)(b.y * 256.f);
  h[6] = (_Float16)(b.z * 256.f); h[7] = (_Float16)(b.w * 256.f);
  *reinterpret_cast<f16x8*>(eh + (size_t)c * DDIM + (size_t)((dg ^ (c & 7)) * 8)) = h;
}

__global__ void init_kernel(const float* __restrict__ x, float* __restrict__ res) {
  size_t i = (size_t)blockIdx.x * blockDim.x + threadIdx.x;
  reinterpret_cast<float4*>(res)[i] = reinterpret_cast<const float4*>(x)[i];
}

// top-2 insert, value-only (codes visited ascending per lane -> strict < keeps first)
__device__ __forceinline__ void ins2(float d, int c, float v[2], int ci[2]) {
  bool l1 = d < v[1];
  bool l0 = d < v[0];
  v[1] = l0 ? v[0] : (l1 ? d : v[1]);  ci[1] = l0 ? ci[0] : (l1 ? c : ci[1]);
  v[0] = l0 ? d : v[0];                ci[0] = l0 ? c : ci[0];
}

// top-2 insert with lexicographic tie-break (value, then lower index)
__device__ __forceinline__ void lexins2(float d, int c, float v[2], int ci[2]) {
  bool l1 = (d < v[1]) || (d == v[1] && c < ci[1]);
  bool l0 = (d < v[0]) || (d == v[0] && c < ci[0]);
  v[1] = l0 ? v[0] : (l1 ? d : v[1]);  ci[1] = l0 ? ci[0] : (l1 ? c : ci[1]);
  v[0] = l0 ? d : v[0];                ci[0] = l0 ? c : ci[0];
}

__global__ __launch_bounds__(512, 1)
void vq_layer_kernel(const float* __restrict__ emb,      // this layer's fp32 codebook
                     const _Float16* __restrict__ eh16,  // this layer's f16 codebook
                     const float* __restrict__ ce,       // this layer's ||e||^2
                     float* __restrict__ res,            // residual (in d_out)
                     float* __restrict__ idx_out,        // this layer's index slice
                     float* __restrict__ loss_part) {    // this layer's partials [NBLK]
  __shared__ __align__(16) _Float16 estage[2][NCHUNK * DDIM];   // 64 KB
  __shared__ __align__(16) float ce_s[KCODES];                  // 4 KB
  __shared__ float cf_s[MT];
  __shared__ float t2v[4][MT][2];
  __shared__ int   t2i[4][MT][2];
  __shared__ int   idx_s[MT];
  __shared__ float rr_v[512];
  __shared__ int   rr_i[512];
  __shared__ unsigned long long fullmask;
  __shared__ float wsum[4];

  const int t      = threadIdx.x;           // 0..511 (8 waves)
  const int lane   = t & 63, w = t >> 6;
  const int tokgrp = w >> 2;                // 0..1 : tokens [tokgrp*32, +32)
  const int cq     = w & 3;                 // 0..3 : codes  [cq*16, +16) per chunk
  const int l15    = lane & 15, lq = lane >> 4;
  const int tok0   = blockIdx.x * MT;

  // issue chunk-0 staging loads early (land under cf/A-split work)
  uint4 sreg[4];
#pragma unroll
  for (int i = 0; i < 4; ++i)
    sreg[i] = *reinterpret_cast<const uint4*>(eh16 + i * 4096 + t * 8);

  // stage ce for the layer (512 thr x 2 floats)
  reinterpret_cast<float2*>(ce_s)[t] = reinterpret_cast<const float2*>(ce)[t];

  // ---- cf = ||res||^2 (EXACT proven r1/r8 arithmetic; waves 0-3 only) ----
  if (t < 256) {
    const int m = t >> 2, p = t & 3;
    const float4* r4 =
        reinterpret_cast<const float4*>(res + (size_t)(tok0 + m) * DDIM + p * 64);
    float s = 0.f;
#pragma unroll
    for (int j = 0; j < 16; ++j) {
      float4 v = r4[j];
      s = fmaf(v.x, v.x, s); s = fmaf(v.y, v.y, s);
      s = fmaf(v.z, v.z, s); s = fmaf(v.w, v.w, s);
    }
    s += __shfl_xor(s, 1);
    s += __shfl_xor(s, 2);
    if (p == 0) cf_s[m] = s;
  }

  // ---- A-split: wave owns tokens [tokgrp*32, +32) as 2 MFMA frags (f16) ----
  f16x8 af[2][8];
#pragma unroll
  for (int mi = 0; mi < 2; ++mi)
#pragma unroll
    for (int ds = 0; ds < 8; ++ds) {
      const float* pr =
          res + (size_t)(tok0 + tokgrp * 32 + mi * 16 + l15) * DDIM + ds * 32 + lq * 8;
      float4 a = *reinterpret_cast<const float4*>(pr);
      float4 b = *reinterpret_cast<const float4*>(pr + 4);
      f16x8 h;
      h[0] = (_Float16)a.x; h[1] = (_Float16)a.y; h[2] = (_Float16)a.z; h[3] = (_Float16)a.w;
      h[4] = (_Float16)b.x; h[5] = (_Float16)b.y; h[6] = (_Float16)b.z; h[7] = (_Float16)b.w;
      af[mi][ds] = h;
    }

  // write chunk 0 into estage[0] (waits on sreg via vmcnt)
#pragma unroll
  for (int i = 0; i < 4; ++i)
    *reinterpret_cast<uint4*>(&estage[0][i * 4096 + t * 8]) = sreg[i];
  __syncthreads();   // B1: ce_s/cf_s/estage[0] visible

  float cfreg[2][4];
#pragma unroll
  for (int mi = 0; mi < 2; ++mi)
#pragma unroll
    for (int r = 0; r < 4; ++r)
      cfreg[mi][r] = cf_s[tokgrp * 32 + mi * 16 + lq * 4 + r];

  float tv[8][2]; int ti[8][2];
#pragma unroll
  for (int s = 0; s < 8; ++s) {
    tv[s][0] = 3.4e38f; tv[s][1] = 3.4e38f; ti[s][0] = 0; ti[s][1] = 0;
  }

  const int crow = cq * 16 + l15;          // this wave's code row in chunk
  const int esw  = (crow & 7) * 8;         // XOR swizzle (8-half groups)

  // ---- K-loop: 16 chunks of 64 codes; ONE barrier per chunk ----
  for (int kc = 0; kc < NCH; ++kc) {
    const int buf = kc & 1;
    if (kc + 1 < NCH) {   // issue next-chunk global loads; hide under MFMA+ds_read
      const _Float16* src = eh16 + (size_t)(kc + 1) * NCHUNK * DDIM;
#pragma unroll
      for (int i = 0; i < 4; ++i)
        sreg[i] = *reinterpret_cast<const uint4*>(src + i * 4096 + t * 8);
    }

    f32x4 acc[2];
    acc[0] = (f32x4){0.f, 0.f, 0.f, 0.f};
    acc[1] = (f32x4){0.f, 0.f, 0.f, 0.f};

    const _Float16* bb = estage[buf];
#pragma unroll
    for (int ds = 0; ds < 8; ++ds) {
      f16x8 b = *reinterpret_cast<const f16x8*>(&bb[crow * DDIM + ((ds * 32 + lq * 8) ^ esw)]);
      acc[0] = __builtin_amdgcn_mfma_f32_16x16x32_f16(af[0][ds], b, acc[0], 0, 0, 0);
      acc[1] = __builtin_amdgcn_mfma_f32_16x16x32_f16(af[1][ds], b, acc[1], 0, 0, 0);
    }

    const int   cg  = kc * NCHUNK + crow;
    const float cev = ce_s[cg];
#pragma unroll
    for (int mi = 0; mi < 2; ++mi)
#pragma unroll
      for (int r = 0; r < 4; ++r) {
        // acc = dot*256; dist = fl((cf+ce) - dot/128), single rounding (r6-proven)
        float d = fmaf(-0.0078125f, acc[mi][r], cfreg[mi][r] + cev);
        ins2(d, cg, tv[mi * 4 + r], ti[mi * 4 + r]);
      }

    if (kc + 1 < NCH) {   // write next chunk into the OTHER buffer (disjoint from reads)
#pragma unroll
      for (int i = 0; i < 4; ++i)
        *reinterpret_cast<uint4*>(&estage[buf ^ 1][i * 4096 + t * 8]) = sreg[i];
    }
    __syncthreads();   // single barrier: next iter reads buf^1 (just written)
  }

  // ---- merge top-2 across the 16-lane code group ----
#pragma unroll
  for (int s = 0; s < 8; ++s) {
#pragma unroll
    for (int off = 1; off <= 8; off <<= 1) {
      float a0 = __shfl_xor(tv[s][0], off), a1 = __shfl_xor(tv[s][1], off);
      int   b0 = __shfl_xor(ti[s][0], off), b1 = __shfl_xor(ti[s][1], off);
      lexins2(a0, b0, tv[s], ti[s]);
      lexins2(a1, b1, tv[s], ti[s]);
    }
    if (l15 == 0) {
      const int mi = s >> 2, r = s & 3;
      const int tok = tokgrp * 32 + mi * 16 + lq * 4 + r;
      t2v[cq][tok][0] = tv[s][0]; t2v[cq][tok][1] = tv[s][1];
      t2i[cq][tok][0] = ti[s][0]; t2i[cq][tok][1] = ti[s][1];
    }
  }
  __syncthreads();   // B2: t2 visible

  // ---- classify: certified unique or full exact re-rank (deterministic ballot) ----
  if (t < MT) {
    float v[2]; int ci[2];
    v[0]  = t2v[0][t][0]; v[1]  = t2v[0][t][1];
    ci[0] = t2i[0][t][0]; ci[1] = t2i[0][t][1];
#pragma unroll
    for (int qd = 1; qd < 4; ++qd) {
      lexins2(t2v[qd][t][0], t2i[qd][t][0], v, ci);
      lexins2(t2v[qd][t][1], t2i[qd][t][1], v, ci);
    }
    idx_s[t] = ci[0];
    unsigned long long bm = __ballot(v[1] - v[0] < DELTA);
    if (t == 0) fullmask = bm;
  }
  __syncthreads();   // B3: idx_s/fullmask visible

  // ---- full exact re-rank for near-tie tokens (proven np-matching path) ----
  unsigned long long fm = fullmask;
  while (fm) {
    const int f = __builtin_ctzll(fm);
    fm &= fm - 1;
    const float cfv = cf_s[f];
    const float* rrow = res + (size_t)(tok0 + f) * DDIM;
    float bestv = 3.4e38f; int besti = 0;
#pragma unroll
    for (int u = 0; u < 2; ++u) {
      int c = t * 2 + u;
      const float4* e4 = reinterpret_cast<const float4*>(emb + (size_t)c * DDIM);
      float acc = 0.f;
#pragma unroll 8
      for (int j = 0; j < 64; ++j) {
        float4 b = e4[j];
        float4 a = *reinterpret_cast<const float4*>(rrow + j * 4);
        acc = fmaf(a.x, b.x, acc); acc = fmaf(a.y, b.y, acc);
        acc = fmaf(a.z, b.z, acc); acc = fmaf(a.w, b.w, acc);
      }
      float dist = (cfv + ce_s[c]) - 2.0f * acc;
      if (dist < bestv) { bestv = dist; besti = c; }   // ascending c: strict <
    }
    rr_v[t] = bestv; rr_i[t] = besti;
    __syncthreads();
    if (t < 64) {
      float vb = rr_v[t]; int ib = rr_i[t];
#pragma unroll
      for (int j = 1; j < 8; ++j) {
        float ov = rr_v[t + j * 64]; int oi = rr_i[t + j * 64];
        if (ov < vb || (ov == vb && oi < ib)) { vb = ov; ib = oi; }
      }
#pragma unroll
      for (int off = 1; off < 64; off <<= 1) {
        float ov = __shfl_xor(vb, off); int oi = __shfl_xor(ib, off);
        if (ov < vb || (ov == vb && oi < ib)) { vb = ov; ib = oi; }
      }
      if (t == 0) idx_s[f] = ib;
    }
    __syncthreads();
  }

  if (t < MT) idx_out[tok0 + t] = (float)idx_s[t];

  // ---- residual update (global) + loss partial (proven r8 path; waves 0-3) ----
  if (t < 256) {
    const int m = t >> 2, p = t & 3;
    const int ci = idx_s[m];
    const float4* e4 = reinterpret_cast<const float4*>(emb + (size_t)ci * DDIM + p * 64);
    float4* r4 = reinterpret_cast<float4*>(res + (size_t)(tok0 + m) * DDIM + p * 64);
    float s = 0.f;
#pragma unroll
    for (int j = 0; j < 16; ++j) {
      float4 r = r4[j], e = e4[j];
      float4 nr = make_float4(r.x - e.x, r.y - e.y, r.z - e.z, r.w - e.w);
      s = fmaf(nr.x, nr.x, s); s = fmaf(nr.y, nr.y, s);
      s = fmaf(nr.z, nr.z, s); s = fmaf(nr.w, nr.w, s);
      r4[j] = nr;
    }
#pragma unroll
    for (int off = 32; off; off >>= 1) s += __shfl_xor(s, off);
    if ((t & 63) == 0) wsum[t >> 6] = s;
  }
  __syncthreads();
  if (t == 0) loss_part[blockIdx.x] = wsum[0] + wsum[1] + wsum[2] + wsum[3];
}

__global__ void final_kernel(const float* __restrict__ x, float* __restrict__ out) {
  size_t i = (size_t)blockIdx.x * blockDim.x + threadIdx.x;
  float4 xv = reinterpret_cast<const float4*>(x)[i];
  float4 r  = reinterpret_cast<float4*>(out)[i];
  reinterpret_cast<float4*>(out)[i] =
      make_float4(xv.x - r.x, xv.y - r.y, xv.z - r.z, xv.w - r.w);
}

__global__ void loss_final_kernel(const float* __restrict__ part, float* __restrict__ loss_out) {
  int t = threadIdx.x;   // 64 threads, QLAYERS*NBLK = 4096 partials
  float s = 0.f;
#pragma unroll
  for (int j = 0; j < QLAYERS * NBLK / 64; ++j) s += part[j * 64 + t];
#pragma unroll
  for (int off = 32; off; off >>= 1) s += __shfl_xor(s, off);
  if (t == 0) *loss_out = s * (1.25f / ((float)NTOK * (float)DDIM));
}

extern "C" void kernel_launch(void* const* d_in, const int* in_sizes, int n_in,
                              void* d_out, int out_size, void* d_ws, size_t ws_size,
                              hipStream_t stream) {
  const float* x   = (const float*)d_in[0];
  const float* emb = (const float*)d_in[1];
  float* out      = (float*)d_out;          // doubles as residual buffer
  float* loss     = out + (size_t)NTOK * DDIM;
  float* idx_base = loss + 1;

  _Float16* eh16   = (_Float16*)d_ws;                                   // 4 MB
  float* ce        = (float*)(eh16 + (size_t)QLAYERS * KCODES * DDIM);  // 32 KB
  float* loss_part = ce + (size_t)QLAYERS * KCODES;                     // 16 KB

  split16_kernel<<<QLAYERS * KCODES * 32 / 256, 256, 0, stream>>>(emb, eh16);
  ce_kernel<<<QLAYERS * KCODES * 64 / 256, 256, 0, stream>>>(emb, ce);
  init_kernel<<<NTOK * DDIM / 4 / 256, 256, 0, stream>>>(x, out);
  for (int q = 0; q < QLAYERS; ++q) {
    vq_layer_kernel<<<NBLK, 512, 0, stream>>>(
        emb + (size_t)q * KCODES * DDIM, eh16 + (size_t)q * KCODES * DDIM,
        ce + (size_t)q * KCODES, out,
        idx_base + (size_t)q * NTOK, loss_part + (size_t)q * NBLK);
  }
  final_kernel<<<NTOK * DDIM / 4 / 256, 256, 0, stream>>>(x, out);
  loss_final_kernel<<<1, 64, 0, stream>>>(loss_part, loss);
}

// Round 11
// 1705.604 us; speedup vs baseline: 2.9921x; 1.4204x over previous
//
#include <hip/hip_runtime.h>

// Problem constants (B=64, T=512, D=256, Q=8, K=1024)
#define NTOK   32768
#define DDIM   256
#define KCODES 1024
#define QLAYERS 8

#define MT     64               // tokens per block
#define NCHUNK 32               // codes staged per chunk
#define NCH    (KCODES / NCHUNK)
#define DELTA  4e-4f            // cert margin >> f16-screen worst-case error
#define NBLK   (NTOK / MT)      // 512 blocks

typedef __attribute__((ext_vector_type(8))) _Float16 f16x8;
typedef __attribute__((ext_vector_type(4))) float f32x4;

// d_out: [0,N*D) residual->output | [N*D] loss | [N*D+1,+Q*N) indices (as float)
// d_ws : eh16 [Q*K*D f16, x256-scaled, swizzled] | ce [Q*K f32] | loss_part [Q*NBLK f32]

__global__ void ce_kernel(const float* __restrict__ emb, float* __restrict__ ce) {
  int gid  = blockIdx.x * blockDim.x + threadIdx.x;
  int code = gid >> 6;
  int lane = threadIdx.x & 63;
  float4 v = reinterpret_cast<const float4*>(emb + (size_t)code * DDIM)[lane];
  float s = v.x * v.x + v.y * v.y + v.z * v.z + v.w * v.w;
#pragma unroll
  for (int off = 32; off; off >>= 1) s += __shfl_xor(s, off);
  if (lane == 0) ce[code] = s;
}

// f16 conversion of codebooks, scaled by 256, 16B-group XOR swizzle baked in
__global__ void split16_kernel(const float* __restrict__ emb, _Float16* __restrict__ eh) {
  int g  = blockIdx.x * blockDim.x + threadIdx.x;   // Q*K*32
  int c  = g >> 5;
  int dg = g & 31;
  const float4* p = reinterpret_cast<const float4*>(emb + (size_t)c * DDIM + dg * 8);
  float4 a = p[0], b = p[1];
  f16x8 h;
  h[0] = (_Float16)(a.x * 256.f); h[1] = (_Float16)(a.y * 256.f);
  h[2] = (_Float16)(a.z * 256.f); h[3] = (_Float16)(a.w * 256.f);
  h[4] = (_Float16)(b.x * 256.f); h[5] = (_Float16)(b.y * 256.f);
  h[6] = (_Float16)(b.z * 256.f); h[7] = (_Float16)(b.w * 256.f);
  *reinterpret_cast<f16x8*>(eh + (size_t)c * DDIM + (size_t)((dg ^ (c & 7)) * 8)) = h;
}

__global__ void init_kernel(const float* __restrict__ x, float* __restrict__ res) {
  size_t i = (size_t)blockIdx.x * blockDim.x + threadIdx.x;
  reinterpret_cast<float4*>(res)[i] = reinterpret_cast<const float4*>(x)[i];
}

__device__ __forceinline__ void lexins(float d, int c, float v[3], int ci[3]) {
  bool l2 = (d < v[2]) || (d == v[2] && c < ci[2]);
  bool l1 = (d < v[1]) || (d == v[1] && c < ci[1]);
  bool l0 = (d < v[0]) || (d == v[0] && c < ci[0]);
  v[2] = l1 ? v[1] : (l2 ? d : v[2]);  ci[2] = l1 ? ci[1] : (l2 ? c : ci[2]);
  v[1] = l0 ? v[0] : (l1 ? d : v[1]);  ci[1] = l0 ? ci[0] : (l1 ? c : ci[1]);
  v[0] = l0 ? d : v[0];                ci[0] = l0 ? c : ci[0];
}

// value-only insert (codes visited ascending per lane -> strict < keeps first)
__device__ __forceinline__ void ins3(float d, int c, float v[3], int ci[3]) {
  bool l2 = d < v[2];
  bool l1 = d < v[1];
  bool l0 = d < v[0];
  v[2] = l1 ? v[1] : (l2 ? d : v[2]);  ci[2] = l1 ? ci[1] : (l2 ? c : ci[2]);
  v[1] = l0 ? v[0] : (l1 ? d : v[1]);  ci[1] = l0 ? ci[0] : (l1 ? c : ci[1]);
  v[0] = l0 ? d : v[0];                ci[0] = l0 ? c : ci[0];
}

// EXACT np-matching distance (r1/r3-proven): sequential fmaf chain d=0..255
__device__ __forceinline__ float exact_dist(const float* __restrict__ rrow,
                                            const float* __restrict__ erow,
                                            float cf, float cev) {
  float acc = 0.f;
  const float4* e4 = reinterpret_cast<const float4*>(erow);
  const float4* a4 = reinterpret_cast<const float4*>(rrow);
#pragma unroll 8
  for (int j = 0; j < 64; ++j) {
    float4 b = e4[j], a = a4[j];
    acc = fmaf(a.x, b.x, acc); acc = fmaf(a.y, b.y, acc);
    acc = fmaf(a.z, b.z, acc); acc = fmaf(a.w, b.w, acc);
  }
  float t1 = cf + cev;
  return t1 - 2.0f * acc;
}

__global__ __launch_bounds__(256, 1)
void vq_layer_kernel(const float* __restrict__ emb,      // this layer's fp32 codebook
                     const _Float16* __restrict__ eh16,  // this layer's f16 codebook
                     const float* __restrict__ ce,       // this layer's ||e||^2
                     float* __restrict__ res,            // residual (in d_out)
                     float* __restrict__ idx_out,        // this layer's index slice
                     float* __restrict__ loss_part) {    // this layer's partials [NBLK]
  __shared__ __align__(16) _Float16 estage[2][NCHUNK * DDIM];   // 32 KB
  __shared__ __align__(16) float ce_s[KCODES];                  // 4 KB
  __shared__ float cf_s[MT];
  __shared__ float t3v[MT][3];
  __shared__ int   t3i[MT][3];
  __shared__ int   idx_s[MT];
  __shared__ float rr_v[256];
  __shared__ int   rr_i[256];
  __shared__ unsigned long long fullmask;
  __shared__ float wsum[4];

  const int t    = threadIdx.x;
  const int lane = t & 63, w = t >> 6;
  const int l15  = lane & 15, lq = lane >> 4;
  const int tok0 = blockIdx.x * MT;

  // issue chunk-0 staging loads early (land under cf/A-split work)
  uint4 sreg[4];
#pragma unroll
  for (int i = 0; i < 4; ++i)
    sreg[i] = *reinterpret_cast<const uint4*>(eh16 + i * 2048 + t * 8);

  // stage ce for the layer
  reinterpret_cast<float4*>(ce_s)[t] = reinterpret_cast<const float4*>(ce)[t];

  // ---- cf = ||res||^2 (EXACT r1 arithmetic, res from global) ----
  {
    const int m = t >> 2, p = t & 3;
    const float4* r4 =
        reinterpret_cast<const float4*>(res + (size_t)(tok0 + m) * DDIM + p * 64);
    float s = 0.f;
#pragma unroll
    for (int j = 0; j < 16; ++j) {
      float4 v = r4[j];
      s = fmaf(v.x, v.x, s); s = fmaf(v.y, v.y, s);
      s = fmaf(v.z, v.z, s); s = fmaf(v.w, v.w, s);
    }
    s += __shfl_xor(s, 1);
    s += __shfl_xor(s, 2);
    if (p == 0) cf_s[m] = s;
  }

  // ---- A-split: wave w owns tokens [w*16, w*16+16), f16 frags from global ----
  f16x8 af[8];
#pragma unroll
  for (int ds = 0; ds < 8; ++ds) {
    const float* pr = res + (size_t)(tok0 + w * 16 + l15) * DDIM + ds * 32 + lq * 8;
    float4 a = *reinterpret_cast<const float4*>(pr);
    float4 b = *reinterpret_cast<const float4*>(pr + 4);
    f16x8 h;
    h[0] = (_Float16)a.x; h[1] = (_Float16)a.y; h[2] = (_Float16)a.z; h[3] = (_Float16)a.w;
    h[4] = (_Float16)b.x; h[5] = (_Float16)b.y; h[6] = (_Float16)b.z; h[7] = (_Float16)b.w;
    af[ds] = h;
  }

  // write chunk 0 (ds_write waits on sreg via data dep), then ONE barrier
#pragma unroll
  for (int i = 0; i < 4; ++i)
    *reinterpret_cast<uint4*>(&estage[0][i * 2048 + t * 8]) = sreg[i];
  __syncthreads();   // B1: ce_s/cf_s/estage[0] visible

  float cfreg[4];
#pragma unroll
  for (int r = 0; r < 4; ++r) cfreg[r] = cf_s[w * 16 + lq * 4 + r];

  float tv[4][3]; int ti[4][3];
#pragma unroll
  for (int s = 0; s < 4; ++s)
#pragma unroll
    for (int k = 0; k < 3; ++k) { tv[s][k] = 3.4e38f; ti[s][k] = 0; }

  // ---- K-loop: 32 chunks of 32 codes; ONE barrier per chunk (r10-proven) ----
  for (int kc = 0; kc < NCH; ++kc) {
    const int buf = kc & 1;
    if (kc + 1 < NCH) {   // issue next-chunk loads; latency hides under MFMA
      const _Float16* src = eh16 + (size_t)(kc + 1) * NCHUNK * DDIM;
#pragma unroll
      for (int i = 0; i < 4; ++i)
        sreg[i] = *reinterpret_cast<const uint4*>(src + i * 2048 + t * 8);
    }

    f32x4 acc[2][2];   // [code-frag][ds-parity] -> 4 independent MFMA chains
#pragma unroll
    for (int c2 = 0; c2 < 2; ++c2)
#pragma unroll
      for (int pp = 0; pp < 2; ++pp) acc[c2][pp] = (f32x4){0.f, 0.f, 0.f, 0.f};

    const _Float16* bb = estage[buf];
#pragma unroll
    for (int ds = 0; ds < 8; ++ds) {
      const int col = ds * 32 + lq * 8;
      const int r0  = l15;               // code rows of this chunk
      const int r1  = 16 + l15;
      f16x8 b0 = *reinterpret_cast<const f16x8*>(&bb[r0 * DDIM + (col ^ ((r0 & 7) * 8))]);
      f16x8 b1 = *reinterpret_cast<const f16x8*>(&bb[r1 * DDIM + (col ^ ((r1 & 7) * 8))]);
      acc[0][ds & 1] = __builtin_amdgcn_mfma_f32_16x16x32_f16(af[ds], b0, acc[0][ds & 1], 0, 0, 0);
      acc[1][ds & 1] = __builtin_amdgcn_mfma_f32_16x16x32_f16(af[ds], b1, acc[1][ds & 1], 0, 0, 0);
    }

#pragma unroll
    for (int c2 = 0; c2 < 2; ++c2) {
      const int   cg  = kc * NCHUNK + c2 * 16 + l15;
      const float cev = ce_s[cg];
#pragma unroll
      for (int r = 0; r < 4; ++r) {
        float dot = acc[c2][0][r] + acc[c2][1][r];   // dot * 256
        float d   = fmaf(-0.0078125f, dot, cfreg[r] + cev);
        ins3(d, cg, tv[r], ti[r]);
      }
    }

    if (kc + 1 < NCH) {   // write next chunk into the OTHER buffer (safe: its readers
                          // finished before the barrier at end of iter kc-1)
#pragma unroll
      for (int i = 0; i < 4; ++i)
        *reinterpret_cast<uint4*>(&estage[buf ^ 1][i * 2048 + t * 8]) = sreg[i];
    }
    __syncthreads();   // single barrier: estage[buf] reads done + estage[buf^1] visible
  }

  // ---- merge top-3 across the 16-lane code group (token fully in-wave) ----
#pragma unroll
  for (int s = 0; s < 4; ++s) {
#pragma unroll
    for (int off = 1; off <= 8; off <<= 1) {
      float a0 = __shfl_xor(tv[s][0], off), a1 = __shfl_xor(tv[s][1], off),
            a2 = __shfl_xor(tv[s][2], off);
      int   b0 = __shfl_xor(ti[s][0], off), b1 = __shfl_xor(ti[s][1], off),
            b2 = __shfl_xor(ti[s][2], off);
      lexins(a0, b0, tv[s], ti[s]);
      lexins(a1, b1, tv[s], ti[s]);
      lexins(a2, b2, tv[s], ti[s]);
    }
    if (l15 == 0) {
      const int tok = w * 16 + lq * 4 + s;
      t3v[tok][0] = tv[s][0]; t3v[tok][1] = tv[s][1]; t3v[tok][2] = tv[s][2];
      t3i[tok][0] = ti[s][0]; t3i[tok][1] = ti[s][1]; t3i[tok][2] = ti[s][2];
    }
  }
  __syncthreads();

  // ---- classify + cheap exact re-rank (wave 0; deterministic ballot) ----
  if (t < MT) {
    float v0 = t3v[t][0], v1 = t3v[t][1], v2 = t3v[t][2];
    int   c0 = t3i[t][0], c1 = t3i[t][1];
    int best = c0;
    bool needfull = false;
    if (v1 - v0 >= DELTA) {
      // certified unique
    } else if (v2 - v0 >= DELTA) {   // exactly {c0, c1} candidates
      const float* rrow = res + (size_t)(tok0 + t) * DDIM;
      int ia = min(c0, c1), ib = max(c0, c1);
      float da = exact_dist(rrow, emb + (size_t)ia * DDIM, cf_s[t], ce_s[ia]);
      float db = exact_dist(rrow, emb + (size_t)ib * DDIM, cf_s[t], ce_s[ib]);
      best = (db < da) ? ib : ia;    // tie -> lower index
    } else {
      needfull = true;
    }
    idx_s[t] = best;
    unsigned long long bm = __ballot(needfull);
    if (t == 0) fullmask = bm;
  }
  __syncthreads();

  // ---- full exact re-rank for rare ambiguous tokens (proven path) ----
  unsigned long long fm = fullmask;
  while (fm) {
    const int f = __builtin_ctzll(fm);
    fm &= fm - 1;
    const float cfv = cf_s[f];
    const float* rrow = res + (size_t)(tok0 + f) * DDIM;
    float bestv = 3.4e38f; int besti = 0;
#pragma unroll
    for (int u = 0; u < 4; ++u) {
      int c = t * 4 + u;
      const float4* e4 = reinterpret_cast<const float4*>(emb + (size_t)c * DDIM);
      float acc = 0.f;
#pragma unroll 8
      for (int j = 0; j < 64; ++j) {
        float4 b = e4[j];
        float4 a = *reinterpret_cast<const float4*>(rrow + j * 4);
        acc = fmaf(a.x, b.x, acc); acc = fmaf(a.y, b.y, acc);
        acc = fmaf(a.z, b.z, acc); acc = fmaf(a.w, b.w, acc);
      }
      float dist = (cfv + ce_s[c]) - 2.0f * acc;
      if (dist < bestv) { bestv = dist; besti = c; }
    }
    rr_v[t] = bestv; rr_i[t] = besti;
    __syncthreads();
    if (t < 64) {
      float vb = rr_v[t]; int ib = rr_i[t];
#pragma unroll
      for (int s = 64; s < 256; s += 64) {
        float ov = rr_v[t + s]; int oi = rr_i[t + s];
        if (ov < vb || (ov == vb && oi < ib)) { vb = ov; ib = oi; }
      }
#pragma unroll
      for (int off = 1; off < 64; off <<= 1) {
        float ov = __shfl_xor(vb, off); int oi = __shfl_xor(ib, off);
        if (ov < vb || (ov == vb && oi < ib)) { vb = ov; ib = oi; }
      }
      if (t == 0) idx_s[f] = ib;
    }
    __syncthreads();
  }

  if (t < MT) idx_out[tok0 + t] = (float)idx_s[t];

  // ---- residual update (global) + loss partial ----
  {
    const int m = t >> 2, p = t & 3;
    const int ci = idx_s[m];
    const float4* e4 = reinterpret_cast<const float4*>(emb + (size_t)ci * DDIM + p * 64);
    float4* r4 = reinterpret_cast<float4*>(res + (size_t)(tok0 + m) * DDIM + p * 64);
    float s = 0.f;
#pragma unroll
    for (int j = 0; j < 16; ++j) {
      float4 r = r4[j], e = e4[j];
      float4 nr = make_float4(r.x - e.x, r.y - e.y, r.z - e.z, r.w - e.w);
      s = fmaf(nr.x, nr.x, s); s = fmaf(nr.y, nr.y, s);
      s = fmaf(nr.z, nr.z, s); s = fmaf(nr.w, nr.w, s);
      r4[j] = nr;
    }
#pragma unroll
    for (int off = 32; off; off >>= 1) s += __shfl_xor(s, off);
    if ((t & 63) == 0) wsum[w] = s;
  }
  __syncthreads();
  if (t == 0) loss_part[blockIdx.x] = wsum[0] + wsum[1] + wsum[2] + wsum[3];
}

__global__ void final_kernel(const float* __restrict__ x, float* __restrict__ out) {
  size_t i = (size_t)blockIdx.x * blockDim.x + threadIdx.x;
  float4 xv = reinterpret_cast<const float4*>(x)[i];
  float4 r  = reinterpret_cast<float4*>(out)[i];
  reinterpret_cast<float4*>(out)[i] =
      make_float4(xv.x - r.x, xv.y - r.y, xv.z - r.z, xv.w - r.w);
}

__global__ void loss_final_kernel(const float* __restrict__ part, float* __restrict__ loss_out) {
  int t = threadIdx.x;   // 64 threads, QLAYERS*NBLK = 4096 partials
  float s = 0.f;
#pragma unroll
  for (int j = 0; j < QLAYERS * NBLK / 64; ++j) s += part[j * 64 + t];
#pragma unroll
  for (int off = 32; off; off >>= 1) s += __shfl_xor(s, off);
  if (t == 0) *loss_out = s * (1.25f / ((float)NTOK * (float)DDIM));
}

extern "C" void kernel_launch(void* const* d_in, const int* in_sizes, int n_in,
                              void* d_out, int out_size, void* d_ws, size_t ws_size,
                              hipStream_t stream) {
  const float* x   = (const float*)d_in[0];
  const float* emb = (const float*)d_in[1];
  float* out      = (float*)d_out;          // doubles as residual buffer
  float* loss     = out + (size_t)NTOK * DDIM;
  float* idx_base = loss + 1;

  _Float16* eh16   = (_Float16*)d_ws;                                   // 4 MB
  float* ce        = (float*)(eh16 + (size_t)QLAYERS * KCODES * DDIM);  // 32 KB
  float* loss_part = ce + (size_t)QLAYERS * KCODES;                     // 16 KB

  split16_kernel<<<QLAYERS * KCODES * 32 / 256, 256, 0, stream>>>(emb, eh16);
  ce_kernel<<<QLAYERS * KCODES * 64 / 256, 256, 0, stream>>>(emb, ce);
  init_kernel<<<NTOK * DDIM / 4 / 256, 256, 0, stream>>>(x, out);
  for (int q = 0; q < QLAYERS; ++q) {
    vq_layer_kernel<<<NBLK, 256, 0, stream>>>(
        emb + (size_t)q * KCODES * DDIM, eh16 + (size_t)q * KCODES * DDIM,
        ce + (size_t)q * KCODES, out,
        idx_base + (size_t)q * NTOK, loss_part + (size_t)q * NBLK);
  }
  final_kernel<<<NTOK * DDIM / 4 / 256, 256, 0, stream>>>(x, out);
  loss_final_kernel<<<1, 64, 0, stream>>>(loss_part, loss);
}